// Round 1
// baseline (1037.840 us; speedup 1.0000x reference)
//
#include <hip/hip_runtime.h>

// ---------------------------------------------------------------------------
// GIN encoder: 4 x { agg = h + scatter_sum(h[src] -> dst); h = BN(ReLU(ReLU(agg@W1+b1)@W2+b2)) }
// then global_add_pool by (sorted) batch_idx, then ReLU(g@Wp+bp).
// All fp32. CSR built per call (deterministic work). No float atomics on the
// feature path.
// ---------------------------------------------------------------------------

__global__ __launch_bounds__(256) void hist_kernel(const int* __restrict__ dst,
                                                   int* __restrict__ counts, int E) {
  int e = blockIdx.x * 256 + threadIdx.x;
  if (e < E) atomicAdd(&counts[dst[e]], 1);
}

__global__ __launch_bounds__(1024) void scan_kernel(const int* __restrict__ counts,
                                                    int* __restrict__ offsets, int n) {
  __shared__ int tmp[1024];
  __shared__ int carry_s;
  int t = threadIdx.x;
  if (t == 0) { offsets[0] = 0; carry_s = 0; }
  __syncthreads();
  for (int base = 0; base < n; base += 1024) {
    int v = (base + t < n) ? counts[base + t] : 0;
    tmp[t] = v;
    __syncthreads();
    for (int off = 1; off < 1024; off <<= 1) {
      int x = (t >= off) ? tmp[t - off] : 0;
      __syncthreads();
      tmp[t] += x;
      __syncthreads();
    }
    int inc = tmp[t] + carry_s;
    if (base + t < n) offsets[base + t + 1] = inc;
    __syncthreads();
    if (t == 1023) carry_s = inc;
    __syncthreads();
  }
}

__global__ __launch_bounds__(256) void copy_int_kernel(const int* __restrict__ a,
                                                       int* __restrict__ b, int n) {
  int i = blockIdx.x * 256 + threadIdx.x;
  if (i < n) b[i] = a[i];
}

__global__ __launch_bounds__(256) void fill_kernel(const int* __restrict__ src,
                                                   const int* __restrict__ dst,
                                                   int* cursor, int* __restrict__ srcs, int E) {
  int e = blockIdx.x * 256 + threadIdx.x;
  if (e < E) {
    int p = atomicAdd(&cursor[dst[e]], 1);
    srcs[p] = src[e];
  }
}

// agg[n] = h[n] + sum_{e in CSR[n]} h[srcs[e]]  -- one wave per node, float2/lane
__global__ __launch_bounds__(256) void aggregate_kernel(const float* __restrict__ H,
                                                        const int* __restrict__ offsets,
                                                        const int* __restrict__ srcs,
                                                        float* __restrict__ out, int n) {
  int idx = blockIdx.x * 256 + threadIdx.x;
  int node = idx >> 6;
  int lane = idx & 63;
  if (node >= n) return;
  const float2* H2 = (const float2*)H;
  float2 acc = H2[node * 64 + lane];
  int e0 = offsets[node], e1 = offsets[node + 1];
  for (int e = e0; e < e1; ++e) {
    int s = srcs[e];
    float2 v = H2[s * 64 + lane];
    acc.x += v.x;
    acc.y += v.y;
  }
  ((float2*)out)[node * 64 + lane] = acc;
}

// C = ReLU(A @ W + b), A: M x 128, W: 128 x 128 (row major), C: M x 128
// block: 32 rows x 128 cols, 256 threads, acc[4][4]/thread. LDS: 64KB W + 16KB A = 80KB -> 2 blocks/CU.
__global__ __launch_bounds__(256, 2) void gemm_relu_kernel(const float* __restrict__ A,
                                                           const float* __restrict__ W,
                                                           const float* __restrict__ bias,
                                                           float* __restrict__ C, int M) {
  __shared__ float4 sW4[128 * 32];
  __shared__ float4 sA4[32 * 32];
  int t = threadIdx.x;
  const float4* W4 = (const float4*)W;
  for (int i = t; i < 128 * 32; i += 256) sW4[i] = W4[i];

  int rbase = blockIdx.x * 32;
  {
    int r = t >> 3;
    int cb4 = (t & 7) * 4;  // float4 index within row
    int rg = rbase + r;
    const float4* Arow = (const float4*)(A + (size_t)rg * 128);
#pragma unroll
    for (int j = 0; j < 4; ++j) {
      float4 v = (rg < M) ? Arow[cb4 + j] : make_float4(0.f, 0.f, 0.f, 0.f);
      sA4[r * 32 + cb4 + j] = v;
    }
  }
  __syncthreads();

  int rq = t >> 5, cq = t & 31;
  int r0 = rq * 4;
  float4 b4 = ((const float4*)bias)[cq];
  float acc[4][4];
#pragma unroll
  for (int i = 0; i < 4; ++i) {
    acc[i][0] = b4.x; acc[i][1] = b4.y; acc[i][2] = b4.z; acc[i][3] = b4.w;
  }
  const float* sA = (const float*)sA4;
#pragma unroll 8
  for (int k = 0; k < 128; ++k) {
    float4 w = sW4[k * 32 + cq];
#pragma unroll
    for (int i = 0; i < 4; ++i) {
      float a = sA[(r0 + i) * 128 + k];
      acc[i][0] = fmaf(a, w.x, acc[i][0]);
      acc[i][1] = fmaf(a, w.y, acc[i][1]);
      acc[i][2] = fmaf(a, w.z, acc[i][2]);
      acc[i][3] = fmaf(a, w.w, acc[i][3]);
    }
  }
#pragma unroll
  for (int i = 0; i < 4; ++i) {
    int rg = rbase + r0 + i;
    if (rg < M) {
      float4 o;
      o.x = fmaxf(acc[i][0], 0.f);
      o.y = fmaxf(acc[i][1], 0.f);
      o.z = fmaxf(acc[i][2], 0.f);
      o.w = fmaxf(acc[i][3], 0.f);
      ((float4*)(C + (size_t)rg * 128))[cq] = o;
    }
  }
}

// per-column sum and sum-of-squares over M rows (256-row chunks per block)
__global__ __launch_bounds__(256) void bn_stats_kernel(const float* __restrict__ H,
                                                       float* sums, float* sumsq, int M) {
  int t = threadIdx.x;
  int c = t & 127;
  int r = blockIdx.x * 256 + (t >> 7);
  int rend = min(blockIdx.x * 256 + 256, M);
  float s = 0.f, sq = 0.f;
  for (; r < rend; r += 2) {
    float v = H[(size_t)r * 128 + c];
    s += v;
    sq += v * v;
  }
  __shared__ float red[512];
  red[t] = s;
  red[t + 256] = sq;
  __syncthreads();
  if (t < 128) {
    atomicAdd(&sums[c], red[t] + red[t + 128]);
    atomicAdd(&sumsq[c], red[t + 256] + red[t + 384]);
  }
}

__global__ void bn_finalize_kernel(const float* __restrict__ sums, const float* __restrict__ sumsq,
                                   const float* __restrict__ gamma, const float* __restrict__ beta,
                                   float* scale, float* shift, float invM) {
  int c = threadIdx.x;
  float mean = sums[c] * invM;
  float var = fmaxf(sumsq[c] * invM - mean * mean, 0.f);
  float sc = gamma[c] * rsqrtf(var + 1e-5f);
  scale[c] = sc;
  shift[c] = beta[c] - mean * sc;
}

__global__ __launch_bounds__(256) void bn_apply_kernel(float* __restrict__ H,
                                                       const float* __restrict__ scale,
                                                       const float* __restrict__ shift, int total4) {
  int i = blockIdx.x * 256 + threadIdx.x;
  int stride = gridDim.x * 256;
  for (; i < total4; i += stride) {
    float4 v = ((float4*)H)[i];
    int c0 = (i & 31) << 2;
    v.x = v.x * scale[c0] + shift[c0];
    v.y = v.y * scale[c0 + 1] + shift[c0 + 1];
    v.z = v.z * scale[c0 + 2] + shift[c0 + 2];
    v.w = v.w * scale[c0 + 3] + shift[c0 + 3];
    ((float4*)H)[i] = v;
  }
}

// batch_idx is sorted: block per graph, binary search the node range, no atomics
__global__ __launch_bounds__(256) void pool_kernel(const float* __restrict__ H,
                                                   const int* __restrict__ batch,
                                                   float* __restrict__ G, int M) {
  int gid = blockIdx.x;
  int lo = 0, hi = M;
  while (lo < hi) { int mid = (lo + hi) >> 1; if (batch[mid] < gid) lo = mid + 1; else hi = mid; }
  int s = lo;
  lo = 0; hi = M;
  while (lo < hi) { int mid = (lo + hi) >> 1; if (batch[mid] < gid + 1) lo = mid + 1; else hi = mid; }
  int e = lo;
  int t = threadIdx.x;
  int c = t & 127;
  float acc = 0.f;
  for (int r = s + (t >> 7); r < e; r += 2) acc += H[(size_t)r * 128 + c];
  __shared__ float red[256];
  red[t] = acc;
  __syncthreads();
  if (t < 128) G[gid * 128 + t] = red[t] + red[t + 128];
}

// out = ReLU(G @ Wp + bp), G: 256 x 128
__global__ __launch_bounds__(128) void proj_kernel(const float* __restrict__ G,
                                                   const float* __restrict__ Wp,
                                                   const float* __restrict__ bp,
                                                   float* __restrict__ out) {
  int gid = blockIdx.x;
  int c = threadIdx.x;
  __shared__ float g[128];
  g[c] = G[gid * 128 + c];
  __syncthreads();
  float acc = bp[c];
#pragma unroll 8
  for (int k = 0; k < 128; ++k) acc = fmaf(g[k], Wp[k * 128 + c], acc);
  out[gid * 128 + c] = fmaxf(acc, 0.f);
}

extern "C" void kernel_launch(void* const* d_in, const int* in_sizes, int n_in,
                              void* d_out, int out_size, void* d_ws, size_t ws_size,
                              hipStream_t stream) {
  const float* x = (const float*)d_in[0];
  const int* ei = (const int*)d_in[1];
  const int* batch = (const int*)d_in[2];
  const float* W1 = (const float*)d_in[3];
  const float* b1 = (const float*)d_in[4];
  const float* W2 = (const float*)d_in[5];
  const float* b2 = (const float*)d_in[6];
  const float* gamma = (const float*)d_in[7];
  const float* beta = (const float*)d_in[8];
  const float* Wp = (const float*)d_in[9];
  const float* bp = (const float*)d_in[10];
  float* out = (float*)d_out;

  int M = in_sizes[0] / 128;         // 50000 nodes
  int E = in_sizes[1] / 2;           // 800000 edges
  int L = in_sizes[3] / (128 * 128); // 4 layers
  int G = out_size / 128;            // 256 graphs
  const int* srcp = ei;
  const int* dstp = ei + E;

  char* w = (char*)d_ws;
  float* bufA = (float*)w;  w += (size_t)M * 128 * 4;
  float* bufB = (float*)w;  w += (size_t)M * 128 * 4;
  int* counts = (int*)w;    w += (size_t)M * 4;
  int* offsets = (int*)w;   w += (size_t)(M + 1) * 4;
  int* cursor = (int*)w;    w += (size_t)M * 4;
  int* srcs = (int*)w;      w += (size_t)E * 4;
  float* gbuf = (float*)w;  w += (size_t)G * 128 * 4;
  float* stats = (float*)w; w += 4 * 128 * 4;
  float* sums = stats;
  float* sumsq = stats + 128;
  float* scale = stats + 256;
  float* shift = stats + 384;

  // ---- CSR build (once per call) ----
  hipMemsetAsync(counts, 0, (size_t)M * 4, stream);
  hist_kernel<<<(E + 255) / 256, 256, 0, stream>>>(dstp, counts, E);
  scan_kernel<<<1, 1024, 0, stream>>>(counts, offsets, M);
  copy_int_kernel<<<(M + 255) / 256, 256, 0, stream>>>(offsets, cursor, M);
  fill_kernel<<<(E + 255) / 256, 256, 0, stream>>>(srcp, dstp, cursor, srcs, E);

  float invM = 1.0f / (float)M;
  const float* h = x;
  for (int l = 0; l < L; ++l) {
    float* aggbuf = (l & 1) ? bufB : bufA;
    float* tbuf = (l & 1) ? bufA : bufB;
    aggregate_kernel<<<(M * 64 + 255) / 256, 256, 0, stream>>>(h, offsets, srcs, aggbuf, M);
    gemm_relu_kernel<<<(M + 31) / 32, 256, 0, stream>>>(aggbuf, W1 + (size_t)l * 128 * 128,
                                                        b1 + l * 128, tbuf, M);
    gemm_relu_kernel<<<(M + 31) / 32, 256, 0, stream>>>(tbuf, W2 + (size_t)l * 128 * 128,
                                                        b2 + l * 128, aggbuf, M);
    hipMemsetAsync(stats, 0, 2 * 128 * 4, stream);
    bn_stats_kernel<<<(M + 255) / 256, 256, 0, stream>>>(aggbuf, sums, sumsq, M);
    bn_finalize_kernel<<<1, 128, 0, stream>>>(sums, sumsq, gamma + l * 128, beta + l * 128,
                                              scale, shift, invM);
    bn_apply_kernel<<<2048, 256, 0, stream>>>(aggbuf, scale, shift, M * 32);
    h = aggbuf;
  }

  pool_kernel<<<G, 256, 0, stream>>>(h, batch, gbuf, M);
  proj_kernel<<<G, 128, 0, stream>>>(gbuf, Wp, bp, out);
}

// Round 3
// 565.390 us; speedup vs baseline: 1.8356x; 1.8356x over previous
//
#include <hip/hip_runtime.h>

// ---------------------------------------------------------------------------
// GIN encoder, fp16 feature path + MFMA GEMMs (fp32 accumulation everywhere).
// Per layer: aggregate(+fused BN of prev layer) -> gemm1(f16 MFMA, +bias+ReLU)
//            -> gemm2(+bias+ReLU+fused column stats) -> finalize(scale/shift)
// BN apply is folded into the NEXT aggregate: BN(h) summed over {self + deg
// neighbors} = scale*(raw agg) + (1+deg)*shift. Last layer's BN folds into
// the pooling kernel.
// fp16 (not bf16): 10 mantissa bits -> 8x lower rounding error; round 2's
// bf16 version failed absmax 0.875 vs 0.81. Values are O(100) max, fp16-safe.
// ---------------------------------------------------------------------------

typedef __attribute__((ext_vector_type(8))) _Float16 f16x8;
typedef __attribute__((ext_vector_type(4))) float f32x4;

static __device__ __forceinline__ float h2f(unsigned short u) {
  return (float)__builtin_bit_cast(_Float16, u);
}
static __device__ __forceinline__ unsigned short f2h(float f) {
  return __builtin_bit_cast(unsigned short, (_Float16)f);
}

// ---- CSR build ----
__global__ __launch_bounds__(256) void hist_kernel(const int* __restrict__ dst,
                                                   int* __restrict__ counts, int E) {
  int e = blockIdx.x * 256 + threadIdx.x;
  if (e < E) atomicAdd(&counts[dst[e]], 1);
}

__global__ __launch_bounds__(512) void scan1_kernel(const int* __restrict__ counts,
                                                    int* __restrict__ incl,
                                                    int* __restrict__ bsums, int n) {
  __shared__ int buf[2][512];
  int t = threadIdx.x;
  int i = blockIdx.x * 512 + t;
  buf[0][t] = (i < n) ? counts[i] : 0;
  __syncthreads();
  int cur = 0;
  for (int off = 1; off < 512; off <<= 1) {
    buf[cur ^ 1][t] = buf[cur][t] + ((t >= off) ? buf[cur][t - off] : 0);
    __syncthreads();
    cur ^= 1;
  }
  if (i < n) incl[i] = buf[cur][t];
  if (t == 511) bsums[blockIdx.x] = buf[cur][511];
}

// exclusive scan of nb (<=128) block sums, in place
__global__ __launch_bounds__(128) void scan2_kernel(int* __restrict__ bsums, int nb) {
  __shared__ int buf[2][128];
  int t = threadIdx.x;
  int v = (t < nb) ? bsums[t] : 0;
  buf[0][t] = v;
  __syncthreads();
  int cur = 0;
  for (int off = 1; off < 128; off <<= 1) {
    buf[cur ^ 1][t] = buf[cur][t] + ((t >= off) ? buf[cur][t - off] : 0);
    __syncthreads();
    cur ^= 1;
  }
  if (t < nb) bsums[t] = buf[cur][t] - v;  // exclusive
}

__global__ __launch_bounds__(256) void scan3_kernel(const int* __restrict__ counts,
                                                    const int* __restrict__ incl,
                                                    const int* __restrict__ bsums,
                                                    int* __restrict__ offsets,
                                                    int* __restrict__ cursor, int n) {
  int i = blockIdx.x * 256 + threadIdx.x;
  if (i < n) {
    int total = bsums[i >> 9] + incl[i];
    offsets[i + 1] = total;
    cursor[i] = total - counts[i];
  }
  if (i == 0) offsets[0] = 0;
}

__global__ __launch_bounds__(256) void fill_kernel(const int* __restrict__ src,
                                                   const int* __restrict__ dst,
                                                   int* cursor, int* __restrict__ srcs, int E) {
  int e = blockIdx.x * 256 + threadIdx.x;
  if (e < E) {
    int p = atomicAdd(&cursor[dst[e]], 1);
    srcs[p] = src[e];
  }
}

// ---- dtype prep ----
__global__ __launch_bounds__(256) void cvt_f16_kernel(const float* __restrict__ in,
                                                      unsigned short* __restrict__ out, int n4) {
  int i = blockIdx.x * 256 + threadIdx.x;
  if (i < n4) {
    float4 v = ((const float4*)in)[i];
    ushort4 o;
    o.x = f2h(v.x); o.y = f2h(v.y); o.z = f2h(v.z); o.w = f2h(v.w);
    ((ushort4*)out)[i] = o;
  }
}

// WT[m][n][k] = f16(W_m[k][n]), m in [0, 2L): even=W1 layer m/2, odd=W2 layer m/2
__global__ __launch_bounds__(256) void prep_w_kernel(const float* __restrict__ W1,
                                                     const float* __restrict__ W2,
                                                     unsigned short* __restrict__ WT, int total) {
  int idx = blockIdx.x * 256 + threadIdx.x;
  if (idx >= total) return;
  int m = idx >> 14;
  int rem = idx & 16383;
  int n = rem >> 7, k = rem & 127;
  const float* W = ((m & 1) == 0) ? (W1 + (size_t)(m >> 1) * 16384)
                                  : (W2 + (size_t)(m >> 1) * 16384);
  WT[idx] = f2h(W[k * 128 + n]);
}

__global__ void init_affine_kernel(float* scale, float* shift) {
  int c = threadIdx.x;
  scale[c] = 1.f;
  shift[c] = 0.f;
}

// ---- aggregate with fused BN of the previous layer ----
// out[i] = f16( scale[c] * (h[i] + sum_j h[srcs]) + (1+deg_i)*shift[c] )
__global__ __launch_bounds__(256) void aggregate_bn_kernel(
    const unsigned short* __restrict__ H, const int* __restrict__ offsets,
    const int* __restrict__ srcs, const float* __restrict__ scale,
    const float* __restrict__ shift, unsigned short* __restrict__ out, int n) {
  int idx = blockIdx.x * 256 + threadIdx.x;
  int node = idx >> 6, lane = idx & 63;
  if (node >= n) return;
  const unsigned int* H1 = (const unsigned int*)H;
  unsigned int self = H1[node * 64 + lane];
  float ax = h2f(self & 0xffffu), ay = h2f(self >> 16);
  int e0 = offsets[node], e1 = offsets[node + 1];
  int e = e0;
  for (; e + 4 <= e1; e += 4) {
    int s0 = srcs[e], s1 = srcs[e + 1], s2 = srcs[e + 2], s3 = srcs[e + 3];
    unsigned int v0 = H1[s0 * 64 + lane];
    unsigned int v1 = H1[s1 * 64 + lane];
    unsigned int v2 = H1[s2 * 64 + lane];
    unsigned int v3 = H1[s3 * 64 + lane];
    ax += h2f(v0 & 0xffffu) + h2f(v1 & 0xffffu) + h2f(v2 & 0xffffu) + h2f(v3 & 0xffffu);
    ay += h2f(v0 >> 16) + h2f(v1 >> 16) + h2f(v2 >> 16) + h2f(v3 >> 16);
  }
  for (; e < e1; ++e) {
    unsigned int v = H1[srcs[e] * 64 + lane];
    ax += h2f(v & 0xffffu);
    ay += h2f(v >> 16);
  }
  int c0 = lane * 2;
  float deg1 = (float)(e1 - e0 + 1);
  float ox = ax * scale[c0] + deg1 * shift[c0];
  float oy = ay * scale[c0 + 1] + deg1 * shift[c0 + 1];
  ((unsigned int*)out)[node * 64 + lane] =
      (unsigned int)f2h(ox) | ((unsigned int)f2h(oy) << 16);
}

// ---- MFMA GEMM: C = ReLU(A @ W + bias), A M x 128 f16, WT is W^T (128x128 f16).
// Block = 4 waves x 16 rows = 64 rows. W^T register-resident (32 frags).
// A-frag: lane holds A[row0 + (l&15)][ks*32 + (l>>4)*8 + j], contiguous 16B.
// B-frag: B[k][n] = WT[n][k]; lane holds WT[n*16+(l&15)][ks*32 + (l>>4)*8 + j].
// C/D: col = lane&15, row = (lane>>4)*4 + reg   [m89-verified, dtype-indep]
template <bool STATS>
__global__ __launch_bounds__(256) void gemm_mfma_kernel(
    const unsigned short* __restrict__ A, const unsigned short* __restrict__ WT,
    const float* __restrict__ bias, unsigned short* __restrict__ C,
    float* __restrict__ sums, float* __restrict__ sumsq, int M) {
  __shared__ float s_sum[128], s_sq[128];
  int t = threadIdx.x;
  if (STATS) {
    if (t < 128) { s_sum[t] = 0.f; s_sq[t] = 0.f; }
    __syncthreads();
  }
  int wave = t >> 6, lane = t & 63;
  int row0 = (blockIdx.x * 4 + wave) * 16;
  int lrow = lane & 15;
  int lk = (lane >> 4) * 8;

  f16x8 b[4][8];
#pragma unroll
  for (int ks = 0; ks < 4; ++ks)
#pragma unroll
    for (int n = 0; n < 8; ++n)
      b[ks][n] = *(const f16x8*)(WT + (size_t)(n * 16 + lrow) * 128 + ks * 32 + lk);

  int arow = min(row0 + lrow, M - 1);
  const unsigned short* Ap = A + (size_t)arow * 128 + lk;

  f32x4 acc[8];
#pragma unroll
  for (int n = 0; n < 8; ++n) acc[n] = (f32x4){0.f, 0.f, 0.f, 0.f};

#pragma unroll
  for (int ks = 0; ks < 4; ++ks) {
    f16x8 a = *(const f16x8*)(Ap + ks * 32);
#pragma unroll
    for (int n = 0; n < 8; ++n)
      acc[n] = __builtin_amdgcn_mfma_f32_16x16x32_f16(a, b[ks][n], acc[n], 0, 0, 0);
  }

  int rbase = row0 + (lane >> 4) * 4;
#pragma unroll
  for (int n = 0; n < 8; ++n) {
    int col = n * 16 + lrow;
    float bia = bias[col];
    float cs = 0.f, cq = 0.f;
#pragma unroll
    for (int r = 0; r < 4; ++r) {
      float v = fmaxf(acc[n][r] + bia, 0.f);
      int rr = rbase + r;
      if (rr < M) {
        C[(size_t)rr * 128 + col] = f2h(v);
        if (STATS) { cs += v; cq += v * v; }
      }
    }
    if (STATS) {
      cs += __shfl_xor(cs, 16); cs += __shfl_xor(cs, 32);
      cq += __shfl_xor(cq, 16); cq += __shfl_xor(cq, 32);
      if ((lane >> 4) == 0) {
        atomicAdd(&s_sum[col], cs);
        atomicAdd(&s_sq[col], cq);
      }
    }
  }
  if (STATS) {
    __syncthreads();
    if (t < 128) {
      atomicAdd(&sums[t], s_sum[t]);
      atomicAdd(&sumsq[t], s_sq[t]);
    }
  }
}

__global__ void bn_finalize_kernel(const float* __restrict__ sums, const float* __restrict__ sumsq,
                                   const float* __restrict__ gamma, const float* __restrict__ beta,
                                   float* scale, float* shift, float invM) {
  int c = threadIdx.x;
  float mean = sums[c] * invM;
  float var = fmaxf(sumsq[c] * invM - mean * mean, 0.f);
  float sc = gamma[c] * rsqrtf(var + 1e-5f);
  scale[c] = sc;
  shift[c] = beta[c] - mean * sc;
}

// ---- pooling with fused BN of the last layer ----
__global__ __launch_bounds__(256) void pool_bn_kernel(
    const unsigned short* __restrict__ H, const int* __restrict__ batch,
    const float* __restrict__ scale, const float* __restrict__ shift,
    float* __restrict__ G, int M) {
  int gid = blockIdx.x;
  int lo = 0, hi = M;
  while (lo < hi) { int mid = (lo + hi) >> 1; if (batch[mid] < gid) lo = mid + 1; else hi = mid; }
  int s = lo;
  lo = 0; hi = M;
  while (lo < hi) { int mid = (lo + hi) >> 1; if (batch[mid] < gid + 1) lo = mid + 1; else hi = mid; }
  int e = lo;
  int t = threadIdx.x, c = t & 127;
  float acc = 0.f;
  for (int r = s + (t >> 7); r < e; r += 2) acc += h2f(H[(size_t)r * 128 + c]);
  __shared__ float red[256];
  red[t] = acc;
  __syncthreads();
  if (t < 128) G[gid * 128 + t] = (red[t] + red[t + 128]) * scale[t] + (float)(e - s) * shift[t];
}

// out = ReLU(G @ Wp + bp), fp32, tiny
__global__ __launch_bounds__(128) void proj_kernel(const float* __restrict__ G,
                                                   const float* __restrict__ Wp,
                                                   const float* __restrict__ bp,
                                                   float* __restrict__ out) {
  int gid = blockIdx.x;
  int c = threadIdx.x;
  __shared__ float g[128];
  g[c] = G[gid * 128 + c];
  __syncthreads();
  float acc = bp[c];
#pragma unroll 8
  for (int k = 0; k < 128; ++k) acc = fmaf(g[k], Wp[k * 128 + c], acc);
  out[gid * 128 + c] = fmaxf(acc, 0.f);
}

extern "C" void kernel_launch(void* const* d_in, const int* in_sizes, int n_in,
                              void* d_out, int out_size, void* d_ws, size_t ws_size,
                              hipStream_t stream) {
  const float* x = (const float*)d_in[0];
  const int* ei = (const int*)d_in[1];
  const int* batch = (const int*)d_in[2];
  const float* W1 = (const float*)d_in[3];
  const float* b1 = (const float*)d_in[4];
  const float* W2 = (const float*)d_in[5];
  const float* b2 = (const float*)d_in[6];
  const float* gamma = (const float*)d_in[7];
  const float* beta = (const float*)d_in[8];
  const float* Wp = (const float*)d_in[9];
  const float* bp = (const float*)d_in[10];
  float* out = (float*)d_out;

  int M = in_sizes[0] / 128;
  int E = in_sizes[1] / 2;
  int L = in_sizes[3] / (128 * 128);
  int G = out_size / 128;
  const int* srcp = ei;
  const int* dstp = ei + E;

  char* w = (char*)d_ws;
  auto alloc = [&](size_t bytes) {
    char* p = w;
    w += (bytes + 255) & ~(size_t)255;
    return p;
  };
  unsigned short* hbuf = (unsigned short*)alloc((size_t)M * 128 * 2);
  unsigned short* aggbuf = (unsigned short*)alloc((size_t)M * 128 * 2);
  unsigned short* tbuf = (unsigned short*)alloc((size_t)M * 128 * 2);
  unsigned short* WT = (unsigned short*)alloc((size_t)L * 2 * 16384 * 2);
  int* counts = (int*)alloc((size_t)M * 4);
  int* incl = (int*)alloc((size_t)M * 4);
  int* bsums = (int*)alloc(128 * 4);
  int* offsets = (int*)alloc((size_t)(M + 1) * 4);
  int* cursor = (int*)alloc((size_t)M * 4);
  int* srcs = (int*)alloc((size_t)E * 4);
  float* gbuf = (float*)alloc((size_t)G * 128 * 4);
  float* stats = (float*)alloc(4 * 128 * 4);
  float* sums = stats;
  float* sumsq = stats + 128;
  float* scale = stats + 256;
  float* shift = stats + 384;

  int nb = (M + 511) / 512;

  // CSR build
  hipMemsetAsync(counts, 0, (size_t)M * 4, stream);
  hist_kernel<<<(E + 255) / 256, 256, 0, stream>>>(dstp, counts, E);
  scan1_kernel<<<nb, 512, 0, stream>>>(counts, incl, bsums, M);
  scan2_kernel<<<1, 128, 0, stream>>>(bsums, nb);
  scan3_kernel<<<(M + 255) / 256, 256, 0, stream>>>(counts, incl, bsums, offsets, cursor, M);
  fill_kernel<<<(E + 255) / 256, 256, 0, stream>>>(srcp, dstp, cursor, srcs, E);

  // dtype prep
  cvt_f16_kernel<<<(M * 32 + 255) / 256, 256, 0, stream>>>(x, hbuf, M * 32);
  prep_w_kernel<<<(L * 2 * 16384 + 255) / 256, 256, 0, stream>>>(W1, W2, WT, L * 2 * 16384);
  init_affine_kernel<<<1, 128, 0, stream>>>(scale, shift);

  float invM = 1.0f / (float)M;
  int gemm_grid = (M + 63) / 64;
  for (int l = 0; l < L; ++l) {
    aggregate_bn_kernel<<<(M * 64 + 255) / 256, 256, 0, stream>>>(hbuf, offsets, srcs, scale,
                                                                  shift, aggbuf, M);
    gemm_mfma_kernel<false><<<gemm_grid, 256, 0, stream>>>(
        aggbuf, WT + (size_t)(2 * l) * 16384, b1 + l * 128, tbuf, nullptr, nullptr, M);
    hipMemsetAsync(stats, 0, 2 * 128 * 4, stream);
    gemm_mfma_kernel<true><<<gemm_grid, 256, 0, stream>>>(
        tbuf, WT + (size_t)(2 * l + 1) * 16384, b2 + l * 128, hbuf, sums, sumsq, M);
    bn_finalize_kernel<<<1, 128, 0, stream>>>(sums, sumsq, gamma + l * 128, beta + l * 128,
                                              scale, shift, invM);
  }

  pool_bn_kernel<<<G, 256, 0, stream>>>(hbuf, batch, scale, shift, gbuf, M);
  proj_kernel<<<G, 128, 0, stream>>>(gbuf, Wp, bp, out);
}